// Round 1
// baseline (877.083 us; speedup 1.0000x reference)
//
#include <hip/hip_runtime.h>
#include <math.h>

#define NLAT 64
#define NLON 128
#define MODEL_DIM 66
#define LEARN 64
#define KPL 8
#define KSIZE 7
#define NFREQ 65
#define TOTAL_K 24
#define HEAD_HID 32
#define FFN_HID 128

#define TWO_PI_OVER_N 0.04908738521234052f

static __device__ __forceinline__ float gelu_f(float v) {
    return 0.5f * v * (1.0f + erff(v * 0.7071067811865475f));
}

// K1: rfft over lon of the 64 learned channels of x.
// Xh[ch][i][f], block per (ch,i) row.
__global__ void k1_fft_x(const float* __restrict__ x, float2* __restrict__ Xh) {
    const int row = blockIdx.x;        // ch*64 + i
    const int ch = row >> 6;
    const int i = row & 63;
    const int t = threadIdx.x;         // 0..127
    __shared__ float sx[NLON];
    __shared__ float ct[NLON], st[NLON];
    float s, c;
    sincosf(TWO_PI_OVER_N * (float)t, &s, &c);
    ct[t] = c; st[t] = s;
    sx[t] = x[(i * NLON + t) * MODEL_DIM + ch];
    __syncthreads();
    if (t < NFREQ) {
        float re = 0.f, im = 0.f;
        for (int p = 0; p < NLON; ++p) {
            const int m = (t * p) & 127;
            const float v = sx[p];
            re = fmaf(v, ct[m], re);
            im = fmaf(-v, st[m], im);
        }
        Xh[row * NFREQ + t] = make_float2(re, im);
    }
}

// K2: P = conj(rfft(psi)) row-wise, with zero-row skip + nz list build.
// P[(k*64+l)*64+i][f]; block per row.
__global__ void k2_fft_psi(const float* __restrict__ psi, float2* __restrict__ P,
                           int* __restrict__ nzc, int* __restrict__ nzi) {
    const int r = blockIdx.x;          // (k*64+l)*64 + i
    const int i = r & 63;
    const int kl = r >> 6;
    const int t = threadIdx.x;         // 0..127
    __shared__ float sx[NLON];
    __shared__ float ct[NLON], st[NLON];
    __shared__ int flag;
    if (t == 0) flag = 0;
    const float v = psi[r * NLON + t];
    sx[t] = v;
    float s, c;
    sincosf(TWO_PI_OVER_N * (float)t, &s, &c);
    ct[t] = c; st[t] = s;
    __syncthreads();
    if (v != 0.0f) flag = 1;
    __syncthreads();
    if (!flag) return;                 // entire row zero: never read downstream
    if (t == 0) {
        const int pos = atomicAdd(&nzc[kl], 1);
        nzi[kl * 64 + pos] = i;
    }
    if (t < NFREQ) {
        float re = 0.f, im = 0.f;
        for (int p = 0; p < NLON; ++p) {
            const int m = (t * p) & 127;
            const float u = sx[p];
            re = fmaf(u, ct[m], re);   // conj(rfft): e^{+i theta}
            im = fmaf(u, st[m], im);
        }
        P[r * NFREQ + t] = make_float2(re, im);
    }
}

// K3: per-frequency contraction over lat_in + channel/k mix, bias into DC bin.
// Out[ch][o][l][f] = sum_{c,k} w[o,c,k] * sum_{i in nz(k,l)} P[k,l,i,f]*In[ch,c,i,f]
template <int CIN>
__global__ __launch_bounds__(520, 1) void k3_contract(
    const float2* __restrict__ P, const float2* __restrict__ In,
    const float* __restrict__ w, const float* __restrict__ bias,
    const int* __restrict__ nzc, const int* __restrict__ nzi,
    float2* __restrict__ Out) {
    const int f = threadIdx.x;                       // 0..64
    const int l = blockIdx.x;                        // 0..63
    const int ch = blockIdx.y * 8 + threadIdx.y;     // 0..63

    float2 acc[KPL];
#pragma unroll
    for (int o = 0; o < KPL; ++o) acc[o] = make_float2(0.f, 0.f);

    const float2* inb = In + (size_t)ch * CIN * NLAT * NFREQ + f;

    for (int k = 0; k < KSIZE; ++k) {
        const int kl = k * 64 + l;
        const int cnt = nzc[kl];
        const int* il = nzi + kl * 64;
        float2 zs[CIN];
#pragma unroll
        for (int c = 0; c < CIN; ++c) zs[c] = make_float2(0.f, 0.f);
        const float2* pb = P + (size_t)kl * 64 * NFREQ + f;
        for (int j = 0; j < cnt; ++j) {
            const int i = il[j];
            const float2 pv = pb[i * NFREQ];
#pragma unroll
            for (int c = 0; c < CIN; ++c) {
                const float2 xv = inb[(c * NLAT + i) * NFREQ];
                zs[c].x = fmaf(pv.x, xv.x, fmaf(-pv.y, xv.y, zs[c].x));
                zs[c].y = fmaf(pv.x, xv.y, fmaf(pv.y, xv.x, zs[c].y));
            }
        }
#pragma unroll
        for (int o = 0; o < KPL; ++o)
#pragma unroll
            for (int c = 0; c < CIN; ++c) {
                const float wv = w[(o * CIN + c) * KSIZE + k];
                acc[o].x = fmaf(wv, zs[c].x, acc[o].x);
                acc[o].y = fmaf(wv, zs[c].y, acc[o].y);
            }
    }
#pragma unroll
    for (int o = 0; o < KPL; ++o) {
        float2 v = acc[o];
        if (f == 0) v.x += 128.0f * bias[o];   // spatial bias == DC-bin offset
        Out[((size_t)(ch * KPL + o) * NLAT + l) * NFREQ + f] = v;
    }
}

// K4: irfft of one level's spectra into d[l][ch][K][p].
__global__ void k4_irfft(const float2* __restrict__ Ch, float* __restrict__ dbuf, int lvl) {
    const int r = blockIdx.x;          // (ch*8+o)*64 + l
    const int l = r & 63;
    const int o = (r >> 6) & 7;
    const int ch = r >> 9;
    const int t = threadIdx.x;         // 0..127 (= output lon p)
    __shared__ float2 sX[NFREQ];
    __shared__ float ct[NLON], st[NLON];
    float s, c;
    sincosf(TWO_PI_OVER_N * (float)t, &s, &c);
    ct[t] = c; st[t] = s;
    if (t < NFREQ) sX[t] = Ch[r * NFREQ + t];
    __syncthreads();
    float acc = sX[0].x + ((t & 1) ? -sX[64].x : sX[64].x);
    for (int fq = 1; fq < 64; ++fq) {
        const int m = (fq * t) & 127;
        acc += 2.0f * (sX[fq].x * ct[m] - sX[fq].y * st[m]);
    }
    const int K = lvl * 8 + o;
    dbuf[((size_t)(l * 64 + ch) * TOTAL_K + K) * NLON + t] = acc * (1.0f / 128.0f);
}

// K5: fused head-MLP + residual + FFN + residual. Block = (l, 8-lon tile).
__global__ __launch_bounds__(256, 1) void k5_head_ffn(
    const float* __restrict__ dbuf, const float* __restrict__ x,
    const float* __restrict__ hw1, const float* __restrict__ hb1,
    const float* __restrict__ hw2, const float* __restrict__ hb2,
    const float* __restrict__ fw0, const float* __restrict__ fb0,
    const float* __restrict__ fw1, const float* __restrict__ fb1,
    float* __restrict__ out) {
    const int l = blockIdx.x;
    const int pt = blockIdx.y;
    const int t = threadIdx.x;     // 256
    const int pos = t >> 5;        // 0..7
    const int lane = t & 31;
    const int p = pt * 8 + pos;

    __shared__ float sf[8][1537];          // feats per pos: [ch*24+K]
    __shared__ float sxl2[8][LEARN];
    __shared__ float sh[8][FFN_HID];

    for (int idx = t; idx < 1536 * 8; idx += 256) {
        const int row = idx >> 3;
        const int pp = idx & 7;
        sf[pp][row] = dbuf[((size_t)l * 1536 + row) * NLON + pt * 8 + pp];
    }
    __syncthreads();

    // head MLP: ch = lane and lane+32
#pragma unroll
    for (int s2 = 0; s2 < 2; ++s2) {
        const int ch = lane + 32 * s2;
        const int n = ch >> 4;
        float fr[TOTAL_K];
#pragma unroll
        for (int k = 0; k < TOTAL_K; ++k) fr[k] = sf[pos][ch * TOTAL_K + k];
        float ho = hb2[n];
        for (int m = 0; m < HEAD_HID; ++m) {
            float a = hb1[n * HEAD_HID + m];
#pragma unroll
            for (int k = 0; k < TOTAL_K; ++k)
                a = fmaf(fr[k], hw1[(n * TOTAL_K + k) * HEAD_HID + m], a);
            ho = fmaf(gelu_f(a), hw2[n * HEAD_HID + m], ho);
        }
        sxl2[pos][ch] = ho + x[(l * NLON + p) * MODEL_DIM + ch];
    }
    __syncthreads();

    const float sc0 = x[(l * NLON + p) * MODEL_DIM + 64];
    const float sc1 = x[(l * NLON + p) * MODEL_DIM + 65];

#pragma unroll
    for (int mm = 0; mm < 4; ++mm) {
        const int m = lane + 32 * mm;
        float a = fb0[m];
        for (int k = 0; k < LEARN; ++k)
            a = fmaf(sxl2[pos][k], fw0[k * FFN_HID + m], a);
        a = fmaf(sc0, fw0[64 * FFN_HID + m], a);
        a = fmaf(sc1, fw0[65 * FFN_HID + m], a);
        sh[pos][m] = gelu_f(a);
    }
    __syncthreads();

#pragma unroll
    for (int s2 = 0; s2 < 2; ++s2) {
        const int dch = lane + 32 * s2;
        float a = fb1[dch];
        for (int m = 0; m < FFN_HID; ++m)
            a = fmaf(sh[pos][m], fw1[m * LEARN + dch], a);
        out[(l * NLON + p) * MODEL_DIM + dch] = a + sxl2[pos][dch];
    }
    if (lane < 2) out[(l * NLON + p) * MODEL_DIM + 64 + lane] = lane ? sc1 : sc0;
}

extern "C" void kernel_launch(void* const* d_in, const int* in_sizes, int n_in,
                              void* d_out, int out_size, void* d_ws, size_t ws_size,
                              hipStream_t stream) {
    (void)in_sizes; (void)n_in; (void)out_size; (void)ws_size;
    const float* x = (const float*)d_in[0];
    const float* psi[3] = {(const float*)d_in[1], (const float*)d_in[2], (const float*)d_in[3]};
    const float* w[3] = {(const float*)d_in[4], (const float*)d_in[6], (const float*)d_in[8]};
    const float* b[3] = {(const float*)d_in[5], (const float*)d_in[7], (const float*)d_in[9]};
    const float* hw1 = (const float*)d_in[10];
    const float* hb1 = (const float*)d_in[11];
    const float* hw2 = (const float*)d_in[12];
    const float* hb2 = (const float*)d_in[13];
    const float* fw0 = (const float*)d_in[14];
    const float* fb0 = (const float*)d_in[15];
    const float* fw1 = (const float*)d_in[16];
    const float* fb1 = (const float*)d_in[17];
    float* out = (float*)d_out;

    // workspace carve-up (floats/float2s), ~102 MB total
    float2* Xh = (float2*)d_ws;                       // 64*64*65
    float2* P = Xh + 64 * 64 * 65;                    // 7*64*64*65
    float2* bufA = P + 7 * 64 * 64 * 65;              // 64*8*64*65
    float2* bufB = bufA + 64 * 8 * 64 * 65;           // 64*8*64*65
    float* dbuf = (float*)(bufB + 64 * 8 * 64 * 65);  // 64*64*24*128
    int* nzc = (int*)(dbuf + (size_t)64 * 64 * 24 * 128);  // 7*64
    int* nzi = nzc + 7 * 64;                               // 7*64*64

    k1_fft_x<<<dim3(64 * 64), dim3(128), 0, stream>>>(x, Xh);

    for (int lvl = 0; lvl < 3; ++lvl) {
        hipMemsetAsync(nzc, 0, 7 * 64 * sizeof(int), stream);
        k2_fft_psi<<<dim3(7 * 64 * 64), dim3(128), 0, stream>>>(psi[lvl], P, nzc, nzi);
        const float2* ob;
        if (lvl == 0) {
            k3_contract<1><<<dim3(64, 8), dim3(65, 8), 0, stream>>>(P, Xh, w[0], b[0], nzc, nzi, bufA);
            ob = bufA;
        } else if (lvl == 1) {
            k3_contract<8><<<dim3(64, 8), dim3(65, 8), 0, stream>>>(P, bufA, w[1], b[1], nzc, nzi, bufB);
            ob = bufB;
        } else {
            k3_contract<8><<<dim3(64, 8), dim3(65, 8), 0, stream>>>(P, bufB, w[2], b[2], nzc, nzi, bufA);
            ob = bufA;
        }
        k4_irfft<<<dim3(64 * 8 * 64), dim3(128), 0, stream>>>(ob, dbuf, lvl);
    }

    k5_head_ffn<<<dim3(64, 16), dim3(256), 0, stream>>>(
        dbuf, x, hw1, hb1, hw2, hb2, fw0, fb0, fw1, fb1, out);
}

// Round 2
// 704.688 us; speedup vs baseline: 1.2446x; 1.2446x over previous
//
#include <hip/hip_runtime.h>
#include <math.h>

#define NLAT 64
#define NLON 128
#define MODEL_DIM 66
#define LEARN 64
#define KPL 8
#define KSIZE 7
#define NFREQ 65
#define TOTAL_K 24
#define HEAD_HID 32
#define FFN_HID 128

#define TWO_PI_OVER_N 0.04908738521234052f

typedef unsigned long long u64;

static __device__ __forceinline__ float gelu_f(float v) {
    return 0.5f * v * (1.0f + erff(v * 0.7071067811865475f));
}

// K1: rfft over lon of the 64 learned channels of x.
// Xh[ch][i][f], block per (ch,i) row.
__global__ void k1_fft_x(const float* __restrict__ x, float2* __restrict__ Xh) {
    const int row = blockIdx.x;        // ch*64 + i
    const int ch = row >> 6;
    const int i = row & 63;
    const int t = threadIdx.x;         // 0..127
    __shared__ float sx[NLON];
    __shared__ float ct[NLON], st[NLON];
    float s, c;
    sincosf(TWO_PI_OVER_N * (float)t, &s, &c);
    ct[t] = c; st[t] = s;
    sx[t] = x[(i * NLON + t) * MODEL_DIM + ch];
    __syncthreads();
    if (t < NFREQ) {
        float re = 0.f, im = 0.f;
        for (int p = 0; p < NLON; ++p) {
            const int m = (t * p) & 127;
            const float v = sx[p];
            re = fmaf(v, ct[m], re);
            im = fmaf(-v, st[m], im);
        }
        Xh[row * NFREQ + t] = make_float2(re, im);
    }
}

// K2: P = conj(rfft(psi)) row-wise, with zero-row skip + per-(k,l) lat bitmask.
__global__ void k2_fft_psi(const float* __restrict__ psi, float2* __restrict__ P,
                           u64* __restrict__ nzm) {
    const int r = blockIdx.x;          // (k*64+l)*64 + i
    const int i = r & 63;
    const int kl = r >> 6;
    const int t = threadIdx.x;         // 0..127
    __shared__ float sx[NLON];
    __shared__ float ct[NLON], st[NLON];
    __shared__ int flag;
    if (t == 0) flag = 0;
    const float v = psi[r * NLON + t];
    sx[t] = v;
    float s, c;
    sincosf(TWO_PI_OVER_N * (float)t, &s, &c);
    ct[t] = c; st[t] = s;
    __syncthreads();
    if (v != 0.0f) flag = 1;
    __syncthreads();
    if (!flag) return;                 // entire row zero: never read downstream
    if (t == 0) atomicOr(&nzm[kl], 1ull << i);
    if (t < NFREQ) {
        float re = 0.f, im = 0.f;
        for (int p = 0; p < NLON; ++p) {
            const int m = (t * p) & 127;
            const float u = sx[p];
            re = fmaf(u, ct[m], re);   // conj(rfft): e^{+i theta}
            im = fmaf(u, st[m], im);
        }
        P[r * NFREQ + t] = make_float2(re, im);
    }
}

// K3 v2: i-outer union-mask loop. Per In element loaded once per (l,ch),
// accumulated into zs[c][k] for every k with bit i set (scalar branch; masks
// are wave-uniform SGPRs). c split into CIN/CHALF passes to bound registers.
// XCD swizzle: bid&7 = l-octile so each XCD's L2 sees only its In/P slice.
template <int CIN, int CHALF>
__global__ __launch_bounds__(520, 1) void k3_contract(
    const float2* __restrict__ P, const float2* __restrict__ In,
    const float* __restrict__ w, const float* __restrict__ bias,
    const u64* __restrict__ nzm, float2* __restrict__ Out) {
    const int f = threadIdx.x;                   // 0..64
    const int bid = blockIdx.x;                  // 0..511
    const int oct = bid & 7;                     // l-octile -> XCD
    const int lw = (bid >> 3) & 7;
    const int chg = bid >> 6;
    const int l = oct * 8 + lw;
    const int ch = chg * 8 + threadIdx.y;

    u64 mk[KSIZE];
    u64 uni = 0;
#pragma unroll
    for (int k = 0; k < KSIZE; ++k) { mk[k] = nzm[k * 64 + l]; uni |= mk[k]; }

    float2 acc[KPL];
#pragma unroll
    for (int o = 0; o < KPL; ++o) acc[o] = make_float2(0.f, 0.f);

    const float2* inb = In + (size_t)ch * CIN * NLAT * NFREQ + f;

    for (int cb = 0; cb < CIN; cb += CHALF) {
        float2 zs[CHALF][KSIZE];
#pragma unroll
        for (int c = 0; c < CHALF; ++c)
#pragma unroll
            for (int k = 0; k < KSIZE; ++k) zs[c][k] = make_float2(0.f, 0.f);

        for (u64 m = uni; m; m &= (m - 1)) {
            const int i = __builtin_ctzll(m);
            float2 xv[CHALF];
#pragma unroll
            for (int c = 0; c < CHALF; ++c)
                xv[c] = inb[((cb + c) * NLAT + i) * NFREQ];
#pragma unroll
            for (int k = 0; k < KSIZE; ++k) {
                if ((mk[k] >> i) & 1) {
                    const float2 pv = P[(((size_t)(k * 64 + l)) * 64 + i) * NFREQ + f];
#pragma unroll
                    for (int c = 0; c < CHALF; ++c) {
                        zs[c][k].x = fmaf(pv.x, xv[c].x, fmaf(-pv.y, xv[c].y, zs[c][k].x));
                        zs[c][k].y = fmaf(pv.x, xv[c].y, fmaf(pv.y, xv[c].x, zs[c][k].y));
                    }
                }
            }
        }
#pragma unroll
        for (int o = 0; o < KPL; ++o)
#pragma unroll
            for (int k = 0; k < KSIZE; ++k)
#pragma unroll
                for (int c = 0; c < CHALF; ++c) {
                    const float wv = w[(o * CIN + cb + c) * KSIZE + k];
                    acc[o].x = fmaf(wv, zs[c][k].x, acc[o].x);
                    acc[o].y = fmaf(wv, zs[c][k].y, acc[o].y);
                }
    }
#pragma unroll
    for (int o = 0; o < KPL; ++o) {
        float2 v = acc[o];
        if (f == 0) v.x += 128.0f * bias[o];   // spatial bias == DC-bin offset
        Out[((size_t)(ch * KPL + o) * NLAT + l) * NFREQ + f] = v;
    }
}

// K4: irfft of one level's spectra into d[l][ch][K][p].
__global__ void k4_irfft(const float2* __restrict__ Ch, float* __restrict__ dbuf, int lvl) {
    const int r = blockIdx.x;          // (ch*8+o)*64 + l
    const int l = r & 63;
    const int o = (r >> 6) & 7;
    const int ch = r >> 9;
    const int t = threadIdx.x;         // 0..127 (= output lon p)
    __shared__ float2 sX[NFREQ];
    __shared__ float ct[NLON], st[NLON];
    float s, c;
    sincosf(TWO_PI_OVER_N * (float)t, &s, &c);
    ct[t] = c; st[t] = s;
    if (t < NFREQ) sX[t] = Ch[r * NFREQ + t];
    __syncthreads();
    float acc = sX[0].x + ((t & 1) ? -sX[64].x : sX[64].x);
    for (int fq = 1; fq < 64; ++fq) {
        const int m = (fq * t) & 127;
        acc += 2.0f * (sX[fq].x * ct[m] - sX[fq].y * st[m]);
    }
    const int K = lvl * 8 + o;
    dbuf[((size_t)(l * 64 + ch) * TOTAL_K + K) * NLON + t] = acc * (1.0f / 128.0f);
}

// K5: fused head-MLP + residual + FFN + residual. Block = (l, 8-lon tile).
__global__ __launch_bounds__(256, 1) void k5_head_ffn(
    const float* __restrict__ dbuf, const float* __restrict__ x,
    const float* __restrict__ hw1, const float* __restrict__ hb1,
    const float* __restrict__ hw2, const float* __restrict__ hb2,
    const float* __restrict__ fw0, const float* __restrict__ fb0,
    const float* __restrict__ fw1, const float* __restrict__ fb1,
    float* __restrict__ out) {
    const int l = blockIdx.x;
    const int pt = blockIdx.y;
    const int t = threadIdx.x;     // 256
    const int pos = t >> 5;        // 0..7
    const int lane = t & 31;
    const int p = pt * 8 + pos;

    __shared__ float sf[8][1537];          // feats per pos: [ch*24+K]
    __shared__ float sxl2[8][LEARN];
    __shared__ float sh[8][FFN_HID];

    for (int idx = t; idx < 1536 * 8; idx += 256) {
        const int row = idx >> 3;
        const int pp = idx & 7;
        sf[pp][row] = dbuf[((size_t)l * 1536 + row) * NLON + pt * 8 + pp];
    }
    __syncthreads();

    // head MLP: ch = lane and lane+32
#pragma unroll
    for (int s2 = 0; s2 < 2; ++s2) {
        const int ch = lane + 32 * s2;
        const int n = ch >> 4;
        float fr[TOTAL_K];
#pragma unroll
        for (int k = 0; k < TOTAL_K; ++k) fr[k] = sf[pos][ch * TOTAL_K + k];
        float ho = hb2[n];
        for (int m = 0; m < HEAD_HID; ++m) {
            float a = hb1[n * HEAD_HID + m];
#pragma unroll
            for (int k = 0; k < TOTAL_K; ++k)
                a = fmaf(fr[k], hw1[(n * TOTAL_K + k) * HEAD_HID + m], a);
            ho = fmaf(gelu_f(a), hw2[n * HEAD_HID + m], ho);
        }
        sxl2[pos][ch] = ho + x[(l * NLON + p) * MODEL_DIM + ch];
    }
    __syncthreads();

    const float sc0 = x[(l * NLON + p) * MODEL_DIM + 64];
    const float sc1 = x[(l * NLON + p) * MODEL_DIM + 65];

#pragma unroll
    for (int mm = 0; mm < 4; ++mm) {
        const int m = lane + 32 * mm;
        float a = fb0[m];
        for (int k = 0; k < LEARN; ++k)
            a = fmaf(sxl2[pos][k], fw0[k * FFN_HID + m], a);
        a = fmaf(sc0, fw0[64 * FFN_HID + m], a);
        a = fmaf(sc1, fw0[65 * FFN_HID + m], a);
        sh[pos][m] = gelu_f(a);
    }
    __syncthreads();

#pragma unroll
    for (int s2 = 0; s2 < 2; ++s2) {
        const int dch = lane + 32 * s2;
        float a = fb1[dch];
        for (int m = 0; m < FFN_HID; ++m)
            a = fmaf(sh[pos][m], fw1[m * LEARN + dch], a);
        out[(l * NLON + p) * MODEL_DIM + dch] = a + sxl2[pos][dch];
    }
    if (lane < 2) out[(l * NLON + p) * MODEL_DIM + 64 + lane] = lane ? sc1 : sc0;
}

extern "C" void kernel_launch(void* const* d_in, const int* in_sizes, int n_in,
                              void* d_out, int out_size, void* d_ws, size_t ws_size,
                              hipStream_t stream) {
    (void)in_sizes; (void)n_in; (void)out_size; (void)ws_size;
    const float* x = (const float*)d_in[0];
    const float* psi[3] = {(const float*)d_in[1], (const float*)d_in[2], (const float*)d_in[3]};
    const float* w[3] = {(const float*)d_in[4], (const float*)d_in[6], (const float*)d_in[8]};
    const float* b[3] = {(const float*)d_in[5], (const float*)d_in[7], (const float*)d_in[9]};
    const float* hw1 = (const float*)d_in[10];
    const float* hb1 = (const float*)d_in[11];
    const float* hw2 = (const float*)d_in[12];
    const float* hb2 = (const float*)d_in[13];
    const float* fw0 = (const float*)d_in[14];
    const float* fb0 = (const float*)d_in[15];
    const float* fw1 = (const float*)d_in[16];
    const float* fb1 = (const float*)d_in[17];
    float* out = (float*)d_out;

    // workspace carve-up (floats/float2s), ~102 MB total
    float2* Xh = (float2*)d_ws;                       // 64*64*65
    float2* P = Xh + 64 * 64 * 65;                    // 7*64*64*65
    float2* bufA = P + 7 * 64 * 64 * 65;              // 64*8*64*65
    float2* bufB = bufA + 64 * 8 * 64 * 65;           // 64*8*64*65
    float* dbuf = (float*)(bufB + 64 * 8 * 64 * 65);  // 64*64*24*128
    u64* nzm = (u64*)(dbuf + (size_t)64 * 64 * 24 * 128);  // 7*64 masks

    k1_fft_x<<<dim3(64 * 64), dim3(128), 0, stream>>>(x, Xh);

    for (int lvl = 0; lvl < 3; ++lvl) {
        hipMemsetAsync(nzm, 0, 7 * 64 * sizeof(u64), stream);
        k2_fft_psi<<<dim3(7 * 64 * 64), dim3(128), 0, stream>>>(psi[lvl], P, nzm);
        const float2* ob;
        if (lvl == 0) {
            k3_contract<1, 1><<<dim3(512), dim3(65, 8), 0, stream>>>(P, Xh, w[0], b[0], nzm, bufA);
            ob = bufA;
        } else if (lvl == 1) {
            k3_contract<8, 4><<<dim3(512), dim3(65, 8), 0, stream>>>(P, bufA, w[1], b[1], nzm, bufB);
            ob = bufB;
        } else {
            k3_contract<8, 4><<<dim3(512), dim3(65, 8), 0, stream>>>(P, bufB, w[2], b[2], nzm, bufA);
            ob = bufA;
        }
        k4_irfft<<<dim3(64 * 8 * 64), dim3(128), 0, stream>>>(ob, dbuf, lvl);
    }

    k5_head_ffn<<<dim3(64, 16), dim3(256), 0, stream>>>(
        dbuf, x, hw1, hb1, hw2, hb2, fw0, fb0, fw1, fb1, out);
}

// Round 3
// 694.153 us; speedup vs baseline: 1.2635x; 1.0152x over previous
//
#include <hip/hip_runtime.h>
#include <math.h>

#define NLAT 64
#define NLON 128
#define MODEL_DIM 66
#define LEARN 64
#define KPL 8
#define KSIZE 7
#define NFREQ 65
#define TOTAL_K 24
#define HEAD_HID 32
#define FFN_HID 128
#define MAXU 20

#define TWO_PI_OVER_N 0.04908738521234052f

typedef unsigned long long u64;

static __device__ __forceinline__ float gelu_f(float v) {
    return 0.5f * v * (1.0f + erff(v * 0.7071067811865475f));
}

// K0: per-(k,l) lat nonzero masks by scanning psi. Block per kl, 4 threads/lat row.
__global__ void k0_mask(const float* __restrict__ psi, u64* __restrict__ nzm) {
    const int kl = blockIdx.x;          // 448
    const int t = threadIdx.x;          // 256
    const int i = t >> 2, q = t & 3;
    const float4* p = (const float4*)(psi + ((size_t)kl * 64 + i) * NLON + q * 32);
    bool nz = false;
#pragma unroll
    for (int u = 0; u < 8; ++u) {
        const float4 v = p[u];
        nz = nz | (v.x != 0.f) | (v.y != 0.f) | (v.z != 0.f) | (v.w != 0.f);
    }
    __shared__ unsigned char fl[64];
    if (t < 64) fl[t] = 0;
    __syncthreads();
    if (nz) fl[i] = 1;
    __syncthreads();
    if (t == 0) {
        u64 m = 0;
        for (int ii = 0; ii < 64; ++ii) if (fl[ii]) m |= (1ull << ii);
        nzm[kl] = m;
    }
}

// K1: rfft over lon of the 64 learned channels of x. Xh[ch][i][f].
__global__ void k1_fft_x(const float* __restrict__ x, float2* __restrict__ Xh) {
    const int row = blockIdx.x;        // ch*64 + i
    const int ch = row >> 6;
    const int i = row & 63;
    const int t = threadIdx.x;         // 0..127
    __shared__ float sx[NLON];
    sx[t] = x[(size_t)(i * NLON + t) * MODEL_DIM + ch];
    __syncthreads();
    if (t < NFREQ) {
        float ws, wc;
        sincosf(TWO_PI_OVER_N * (float)t, &ws, &wc);
        float cr = 1.f, ci = 0.f, re = 0.f, im = 0.f;
        for (int p = 0; p < NLON; ++p) {
            const float v = sx[p];
            re = fmaf(v, cr, re);
            im = fmaf(-v, ci, im);
            const float a = ci * wc;
            const float nr = fmaf(cr, wc, -(ci * ws));
            ci = fmaf(cr, ws, a);
            cr = nr;
        }
        Xh[(size_t)row * NFREQ + t] = make_float2(re, im);
    }
}

// K2: conj(rfft(psi)) for nonzero rows, scattered directly into dense pack:
// Ppack[l][j][f][k] with j = position of lat i in the per-l union list.
__global__ void k2_dft(const float* __restrict__ psi, const u64* __restrict__ nzm,
                       float2* __restrict__ Pp) {
    const int r = blockIdx.x;          // (k*64+l)*64 + i
    const int i = r & 63;
    const int kl = r >> 6;
    const int k = kl >> 6;
    const int l = kl & 63;
    if (!((nzm[kl] >> i) & 1ull)) return;
    u64 uni = 0;
#pragma unroll
    for (int kk = 0; kk < KSIZE; ++kk) uni |= nzm[kk * 64 + l];
    const int j = __popcll(uni & ((1ull << i) - 1ull));
    if (j >= MAXU) return;
    const int t = threadIdx.x;         // 0..127
    __shared__ float sx[NLON];
    sx[t] = psi[(size_t)r * NLON + t];
    __syncthreads();
    if (t < NFREQ) {
        float ws, wc;
        sincosf(TWO_PI_OVER_N * (float)t, &ws, &wc);
        float cr = 1.f, ci = 0.f, re = 0.f, im = 0.f;
        for (int p = 0; p < NLON; ++p) {
            const float u = sx[p];
            re = fmaf(u, cr, re);      // conj(rfft): e^{+i theta}
            im = fmaf(u, ci, im);
            const float a = ci * wc;
            const float nr = fmaf(cr, wc, -(ci * ws));
            ci = fmaf(cr, ws, a);
            cr = nr;
        }
        Pp[((size_t)(l * MAXU + j) * NFREQ + t) * 8 + k] = make_float2(re, im);
    }
}

// K3 v3 pass: unconditional dense j-loop over the union list, KN k-slots.
template <int CIN, int KOFF, int KN>
static __device__ __forceinline__ void k3_pass(
    const float2* __restrict__ inB, const float2* __restrict__ pB,
    u64 uni, int U, const float* __restrict__ w, float2* acc) {
    float2 zs[CIN][KN];
#pragma unroll
    for (int c = 0; c < CIN; ++c)
#pragma unroll
        for (int k = 0; k < KN; ++k) zs[c][k] = make_float2(0.f, 0.f);

    u64 m = uni;
    for (int j = 0; j < U; ++j) {
        const int i = __builtin_ctzll(m);
        m &= m - 1;
        float2 xv[CIN];
        if (CIN == 8) {
            const float4* xp = (const float4*)(inB + (size_t)i * 520);
            *(float4*)&xv[0] = xp[0];
            *(float4*)&xv[2] = xp[1];
            *(float4*)&xv[4] = xp[2];
            *(float4*)&xv[6] = xp[3];
        } else {
            xv[0] = inB[(size_t)i * NFREQ];
        }
        float2 pv[4];
        const float4* pp = (const float4*)(pB + (size_t)j * 520 + KOFF);
        *(float4*)&pv[0] = pp[0];
        *(float4*)&pv[2] = pp[1];
#pragma unroll
        for (int c = 0; c < CIN; ++c)
#pragma unroll
            for (int k = 0; k < KN; ++k) {
                zs[c][k].x = fmaf(pv[k].x, xv[c].x, fmaf(-pv[k].y, xv[c].y, zs[c][k].x));
                zs[c][k].y = fmaf(pv[k].x, xv[c].y, fmaf(pv[k].y, xv[c].x, zs[c][k].y));
            }
    }
#pragma unroll
    for (int o = 0; o < KPL; ++o)
#pragma unroll
        for (int c = 0; c < CIN; ++c)
#pragma unroll
            for (int k = 0; k < KN; ++k) {
                const float wv = w[(o * CIN + c) * KSIZE + KOFF + k];
                acc[o].x = fmaf(wv, zs[c][k].x, acc[o].x);
                acc[o].y = fmaf(wv, zs[c][k].y, acc[o].y);
            }
}

// K3 v3: In layout [ch][i][f][c] (lvl0: Xh [ch][i][f]); Out [ch][l][f][o].
// Grid 520: bid<512 main (f=0..63), bid>=512 Nyquist f=64 blocks.
template <int CIN>
__global__ __launch_bounds__(512, 4) void k3_contract(
    const float2* __restrict__ Pp, const float2* __restrict__ In,
    const float* __restrict__ w, const float* __restrict__ bias,
    const u64* __restrict__ nzm, float2* __restrict__ Out) {
    const int bid = blockIdx.x;
    int f, ch, l;
    if (bid < 512) {
        f = threadIdx.x;
        l = ((bid & 7) << 3) + ((bid >> 3) & 7);   // XCD swizzle on l-octile
        ch = ((bid >> 6) << 3) + threadIdx.y;
    } else {
        f = 64;
        ch = threadIdx.x;
        l = ((bid - 512) << 3) + threadIdx.y;
    }
    u64 uni = 0;
#pragma unroll
    for (int k = 0; k < KSIZE; ++k) uni |= nzm[k * 64 + l];
    const int U = __popcll(uni);

    const float2* inB;
    if (CIN == 8) inB = In + (size_t)ch * 33280 + (size_t)f * 8;
    else          inB = In + (size_t)ch * 4160 + f;
    const float2* pB = Pp + (size_t)l * (MAXU * 520) + (size_t)f * 8;

    float2 acc[KPL];
#pragma unroll
    for (int o = 0; o < KPL; ++o) acc[o] = make_float2(0.f, 0.f);

    k3_pass<CIN, 0, 4>(inB, pB, uni, U, w, acc);
    k3_pass<CIN, 4, 3>(inB, pB, uni, U, w, acc);

    float2 ov[KPL];
#pragma unroll
    for (int o = 0; o < KPL; ++o) {
        ov[o] = acc[o];
        if (f == 0) ov[o].x += 128.0f * bias[o];   // spatial bias == DC-bin offset
    }
    float4* op = (float4*)(Out + ((size_t)ch * 64 + l) * 520 + (size_t)f * 8);
    op[0] = *(const float4*)&ov[0];
    op[1] = *(const float4*)&ov[2];
    op[2] = *(const float4*)&ov[4];
    op[3] = *(const float4*)&ov[6];
}

// K4: irfft. Block per (ch,l); stages all 8 o-spectra (contiguous) in LDS;
// twiddle rotation amortized over 8 outputs/thread.
__global__ __launch_bounds__(128, 8) void k4_irfft(const float2* __restrict__ Ch,
                                                   float* __restrict__ dbuf, int lvl) {
    const int b = blockIdx.x;          // ch*64 + l
    const int ch = b >> 6, l = b & 63;
    const int t = threadIdx.x;         // 0..127 (= output lon p)
    __shared__ float2 sX[520];         // [f][o]
    const float4* src = (const float4*)(Ch + (size_t)b * 520);
    float4* dst = (float4*)sX;
    dst[t] = src[t];
    if (t + 128 < 260) dst[t + 128] = src[t + 128];
    __syncthreads();
    float ws, wc;
    sincosf(TWO_PI_OVER_N * (float)t, &ws, &wc);
    float cr = wc, ci = ws;            // fq = 1
    float av[8];
#pragma unroll
    for (int o = 0; o < 8; ++o) av[o] = 0.f;
    for (int fq = 1; fq < 64; ++fq) {
#pragma unroll
        for (int o = 0; o < 8; ++o) {
            const float2 v = sX[fq * 8 + o];
            av[o] = fmaf(v.x, cr, av[o]);
            av[o] = fmaf(-v.y, ci, av[o]);
        }
        const float a = ci * wc;
        const float nr = fmaf(cr, wc, -(ci * ws));
        ci = fmaf(cr, ws, a);
        cr = nr;
    }
    const float sg = (t & 1) ? -1.f : 1.f;
#pragma unroll
    for (int o = 0; o < 8; ++o) {
        const float res = (sX[o].x + sg * sX[512 + o].x + 2.f * av[o]) * (1.f / 128.f);
        dbuf[(((size_t)l * 64 + ch) * TOTAL_K + lvl * 8 + o) * NLON + t] = res;
    }
}

// K5: fused head-MLP + residual + FFN + residual. Block = (l, 8-lon tile).
__global__ __launch_bounds__(256, 1) void k5_head_ffn(
    const float* __restrict__ dbuf, const float* __restrict__ x,
    const float* __restrict__ hw1, const float* __restrict__ hb1,
    const float* __restrict__ hw2, const float* __restrict__ hb2,
    const float* __restrict__ fw0, const float* __restrict__ fb0,
    const float* __restrict__ fw1, const float* __restrict__ fb1,
    float* __restrict__ out) {
    const int l = blockIdx.x;
    const int pt = blockIdx.y;
    const int t = threadIdx.x;     // 256
    const int pos = t >> 5;        // 0..7
    const int lane = t & 31;
    const int p = pt * 8 + pos;

    __shared__ float sf[8][1537];          // feats per pos: [ch*24+K]
    __shared__ float sxl2[8][LEARN];
    __shared__ float sh[8][FFN_HID];

    for (int idx = t; idx < 1536 * 8; idx += 256) {
        const int row = idx >> 3;
        const int pp = idx & 7;
        sf[pp][row] = dbuf[((size_t)l * 1536 + row) * NLON + pt * 8 + pp];
    }
    __syncthreads();

#pragma unroll
    for (int s2 = 0; s2 < 2; ++s2) {
        const int ch = lane + 32 * s2;
        const int n = ch >> 4;
        float fr[TOTAL_K];
#pragma unroll
        for (int k = 0; k < TOTAL_K; ++k) fr[k] = sf[pos][ch * TOTAL_K + k];
        float ho = hb2[n];
        for (int m = 0; m < HEAD_HID; ++m) {
            float a = hb1[n * HEAD_HID + m];
#pragma unroll
            for (int k = 0; k < TOTAL_K; ++k)
                a = fmaf(fr[k], hw1[(n * TOTAL_K + k) * HEAD_HID + m], a);
            ho = fmaf(gelu_f(a), hw2[n * HEAD_HID + m], ho);
        }
        sxl2[pos][ch] = ho + x[(l * NLON + p) * MODEL_DIM + ch];
    }
    __syncthreads();

    const float sc0 = x[(l * NLON + p) * MODEL_DIM + 64];
    const float sc1 = x[(l * NLON + p) * MODEL_DIM + 65];

#pragma unroll
    for (int mm = 0; mm < 4; ++mm) {
        const int m = lane + 32 * mm;
        float a = fb0[m];
        for (int k = 0; k < LEARN; ++k)
            a = fmaf(sxl2[pos][k], fw0[k * FFN_HID + m], a);
        a = fmaf(sc0, fw0[64 * FFN_HID + m], a);
        a = fmaf(sc1, fw0[65 * FFN_HID + m], a);
        sh[pos][m] = gelu_f(a);
    }
    __syncthreads();

#pragma unroll
    for (int s2 = 0; s2 < 2; ++s2) {
        const int dch = lane + 32 * s2;
        float a = fb1[dch];
        for (int m = 0; m < FFN_HID; ++m)
            a = fmaf(sh[pos][m], fw1[m * LEARN + dch], a);
        out[(l * NLON + p) * MODEL_DIM + dch] = a + sxl2[pos][dch];
    }
    if (lane < 2) out[(l * NLON + p) * MODEL_DIM + 64 + lane] = lane ? sc1 : sc0;
}

extern "C" void kernel_launch(void* const* d_in, const int* in_sizes, int n_in,
                              void* d_out, int out_size, void* d_ws, size_t ws_size,
                              hipStream_t stream) {
    (void)in_sizes; (void)n_in; (void)out_size; (void)ws_size;
    const float* x = (const float*)d_in[0];
    const float* psi[3] = {(const float*)d_in[1], (const float*)d_in[2], (const float*)d_in[3]};
    const float* w[3] = {(const float*)d_in[4], (const float*)d_in[6], (const float*)d_in[8]};
    const float* b[3] = {(const float*)d_in[5], (const float*)d_in[7], (const float*)d_in[9]};
    const float* hw1 = (const float*)d_in[10];
    const float* hb1 = (const float*)d_in[11];
    const float* hw2 = (const float*)d_in[12];
    const float* hb2 = (const float*)d_in[13];
    const float* fw0 = (const float*)d_in[14];
    const float* fb0 = (const float*)d_in[15];
    const float* fw1 = (const float*)d_in[16];
    const float* fb1 = (const float*)d_in[17];
    float* out = (float*)d_out;

    // workspace carve-up, ~92 MB total
    float2* Xh = (float2*)d_ws;                 // 64*64*65            = 266240
    float2* Pp = Xh + 266240;                   // 64*20*65*8          = 665600
    float2* bufA = Pp + 665600;                 // 64*64*65*8          = 2129920
    float2* bufB = bufA + 2129920;              // 64*64*65*8
    float* dbuf = (float*)(bufB + 2129920);     // 64*64*24*128 floats
    u64* nzm = (u64*)(dbuf + (size_t)64 * 64 * 24 * 128);   // 448 masks

    k1_fft_x<<<dim3(64 * 64), dim3(128), 0, stream>>>(x, Xh);

    for (int lvl = 0; lvl < 3; ++lvl) {
        hipMemsetAsync(Pp, 0, (size_t)665600 * sizeof(float2), stream);
        k0_mask<<<dim3(448), dim3(256), 0, stream>>>(psi[lvl], nzm);
        k2_dft<<<dim3(7 * 64 * 64), dim3(128), 0, stream>>>(psi[lvl], nzm, Pp);
        const float2* ob;
        if (lvl == 0) {
            k3_contract<1><<<dim3(520), dim3(64, 8), 0, stream>>>(Pp, Xh, w[0], b[0], nzm, bufA);
            ob = bufA;
        } else if (lvl == 1) {
            k3_contract<8><<<dim3(520), dim3(64, 8), 0, stream>>>(Pp, bufA, w[1], b[1], nzm, bufB);
            ob = bufB;
        } else {
            k3_contract<8><<<dim3(520), dim3(64, 8), 0, stream>>>(Pp, bufB, w[2], b[2], nzm, bufA);
            ob = bufA;
        }
        k4_irfft<<<dim3(64 * 64), dim3(128), 0, stream>>>(ob, dbuf, lvl);
    }

    k5_head_ffn<<<dim3(64, 16), dim3(256), 0, stream>>>(
        dbuf, x, hw1, hb1, hw2, hb2, fw0, fb0, fw1, fb1, out);
}

// Round 5
// 633.833 us; speedup vs baseline: 1.3838x; 1.0952x over previous
//
#include <hip/hip_runtime.h>
#include <math.h>

#define NLAT 64
#define NLON 128
#define MODEL_DIM 66
#define LEARN 64
#define KPL 8
#define KSIZE 7
#define NFREQ 65
#define TOTAL_K 24
#define HEAD_HID 32
#define FFN_HID 128
#define MAXU 20

#define TWO_PI_OVER_N 0.04908738521234052f

typedef unsigned long long u64;

static __device__ __forceinline__ float gelu_f(float v) {
    return 0.5f * v * (1.0f + erff(v * 0.7071067811865475f));
}

// K0: per-(k,l) lat nonzero masks by scanning psi. Block per kl.
__global__ void k0_mask(const float* __restrict__ psi, u64* __restrict__ nzm) {
    const int kl = blockIdx.x;          // 448
    const int t = threadIdx.x;          // 256
    const int i = t >> 2, q = t & 3;
    const float4* p = (const float4*)(psi + ((size_t)kl * 64 + i) * NLON + q * 32);
    bool nz = false;
#pragma unroll
    for (int u = 0; u < 8; ++u) {
        const float4 v = p[u];
        nz = nz | (v.x != 0.f) | (v.y != 0.f) | (v.z != 0.f) | (v.w != 0.f);
    }
    __shared__ unsigned char fl[64];
    if (t < 64) fl[t] = 0;
    __syncthreads();
    if (nz) fl[i] = 1;
    __syncthreads();
    if (t == 0) {
        u64 m = 0;
        for (int ii = 0; ii < 64; ++ii) if (fl[ii]) m |= (1ull << ii);
        nzm[kl] = m;
    }
}

// K1: rfft over lon of the 64 learned channels of x. Xh[ch][i][f]. Exact tables.
__global__ void k1_fft_x(const float* __restrict__ x, float2* __restrict__ Xh) {
    const int row = blockIdx.x;        // ch*64 + i
    const int ch = row >> 6;
    const int i = row & 63;
    const int t = threadIdx.x;         // 0..127
    __shared__ float sx[NLON];
    __shared__ float ct[NLON], st[NLON];
    float s, c;
    sincosf(TWO_PI_OVER_N * (float)t, &s, &c);
    ct[t] = c; st[t] = s;
    sx[t] = x[(size_t)(i * NLON + t) * MODEL_DIM + ch];
    __syncthreads();
    if (t < NFREQ) {
        float re = 0.f, im = 0.f;
        for (int p = 0; p < NLON; ++p) {
            const int m = (t * p) & 127;
            const float v = sx[p];
            re = fmaf(v, ct[m], re);
            im = fmaf(-v, st[m], im);
        }
        Xh[(size_t)row * NFREQ + t] = make_float2(re, im);
    }
}

// K2: conj(rfft(psi)) into dense pack Pp[l][j][k][f] (j over the per-l union
// lat list). One block per (k,l); zero-fills union rows not in this k's mask,
// so no memset pass is needed and every (j<U, k<7) slot is defined.
__global__ void k2_dft(const float* __restrict__ psi, const u64* __restrict__ nzm,
                       float2* __restrict__ Pp) {
    const int kl = blockIdx.x;          // 448
    const int k = kl >> 6, l = kl & 63;
    const int t = threadIdx.x;          // 0..127
    const u64 mk = nzm[kl];
    u64 uni = 0;
#pragma unroll
    for (int kk = 0; kk < KSIZE; ++kk) uni |= nzm[kk * 64 + l];
    __shared__ float sx[NLON];
    __shared__ float ct[NLON], st[NLON];
    float s, c;
    sincosf(TWO_PI_OVER_N * (float)t, &s, &c);
    ct[t] = c; st[t] = s;
    __syncthreads();
    int j = 0;
    for (u64 m = uni; m; m &= m - 1, ++j) {
        if (j >= MAXU) break;
        const int i = __builtin_ctzll(m);
        float2* dst = Pp + ((size_t)(l * MAXU + j) * 8 + k) * NFREQ;
        const bool live = (mk >> i) & 1ull;
        if (live) {                     // uniform branch: barriers legal
            __syncthreads();
            sx[t] = psi[((size_t)kl * 64 + i) * NLON + t];
            __syncthreads();
        }
        if (t < NFREQ) {
            if (live) {
                float re = 0.f, im = 0.f;
                for (int p = 0; p < NLON; ++p) {
                    const int m2 = (t * p) & 127;
                    const float u = sx[p];
                    re = fmaf(u, ct[m2], re);   // conj(rfft): e^{+i theta}
                    im = fmaf(u, st[m2], im);
                }
                dst[t] = make_float2(re, im);
            } else {
                dst[t] = make_float2(0.f, 0.f);
            }
        }
    }
}

// K3 v4: branch-free dense j-loop, lane=f 8B-contiguous loads everywhere.
// In [ch][c][i][f]; Pp [l][j][k][f]; Out [ch][o][l][f] (= next level's In).
// c split into CHALF passes (re-reads only the small XCD-local P).
// Blocks 0..7 handle Nyquist f=64; 8..519 main (f=0..63).
template <int CIN, int CHALF>
__global__ __launch_bounds__(512, 4) void k3_contract(
    const float2* __restrict__ Pp, const float2* __restrict__ In,
    const float* __restrict__ w, const float* __restrict__ bias,
    const u64* __restrict__ nzm, float2* __restrict__ Out) {
    const int bid = blockIdx.x;
    int f, ch, l;
    if (bid >= 8) {
        const int b = bid - 8;
        f = threadIdx.x;
        l = ((b & 7) << 3) | ((b >> 3) & 7);   // XCD swizzle on l-octile
        ch = ((b >> 6) << 3) + threadIdx.y;
    } else {
        f = 64;
        ch = threadIdx.x;
        l = (bid << 3) + threadIdx.y;
    }
    u64 uni = 0;
#pragma unroll
    for (int k = 0; k < KSIZE; ++k) uni |= nzm[k * 64 + l];
    int U = __popcll(uni);
    if (U > MAXU) U = MAXU;

    const float2* inB = In + (size_t)ch * (CIN * NLAT * NFREQ) + f;
    const float2* pB = Pp + (size_t)l * (MAXU * 8 * NFREQ) + f;

    float2 acc[KPL];
#pragma unroll
    for (int o = 0; o < KPL; ++o) acc[o] = make_float2(0.f, 0.f);

    for (int cb = 0; cb < CIN; cb += CHALF) {
        float2 zs[CHALF][KSIZE];
#pragma unroll
        for (int c = 0; c < CHALF; ++c)
#pragma unroll
            for (int k = 0; k < KSIZE; ++k) zs[c][k] = make_float2(0.f, 0.f);

        u64 m = uni;
        for (int j = 0; j < U; ++j) {
            const int i = __builtin_ctzll(m);
            m &= m - 1;
            float2 xv[CHALF];
#pragma unroll
            for (int c = 0; c < CHALF; ++c)
                xv[c] = inB[(size_t)((cb + c) * NLAT + i) * NFREQ];
            float2 pv[KSIZE];
#pragma unroll
            for (int k = 0; k < KSIZE; ++k)
                pv[k] = pB[(size_t)(j * 8 + k) * NFREQ];
#pragma unroll
            for (int c = 0; c < CHALF; ++c)
#pragma unroll
                for (int k = 0; k < KSIZE; ++k) {
                    zs[c][k].x = fmaf(pv[k].x, xv[c].x, fmaf(-pv[k].y, xv[c].y, zs[c][k].x));
                    zs[c][k].y = fmaf(pv[k].x, xv[c].y, fmaf(pv[k].y, xv[c].x, zs[c][k].y));
                }
        }
#pragma unroll
        for (int o = 0; o < KPL; ++o)
#pragma unroll
            for (int c = 0; c < CHALF; ++c)
#pragma unroll
                for (int k = 0; k < KSIZE; ++k) {
                    const float wv = w[(o * CIN + cb + c) * KSIZE + k];
                    acc[o].x = fmaf(wv, zs[c][k].x, acc[o].x);
                    acc[o].y = fmaf(wv, zs[c][k].y, acc[o].y);
                }
    }
#pragma unroll
    for (int o = 0; o < KPL; ++o) {
        float2 v = acc[o];
        if (f == 0) v.x += 128.0f * bias[o];   // spatial bias == DC-bin offset
        Out[((size_t)(ch * KPL + o) * NLAT + l) * NFREQ + f] = v;
    }
}

// K4: irfft. Block per (ch,l). Ch layout is [ch][o][l][f]: stage the 8
// strided o-segments (65 float2 each) into LDS [o][f], then 8 outputs/thread.
__global__ __launch_bounds__(128, 8) void k4_irfft(const float2* __restrict__ Ch,
                                                   float* __restrict__ dbuf, int lvl) {
    const int b = blockIdx.x;          // ch*64 + l
    const int ch = b >> 6, l = b & 63;
    const int t = threadIdx.x;         // 0..127 (= output lon p)
    __shared__ float2 sX[520];         // [o][f]
    __shared__ float ct[NLON], st[NLON];
    float s, c;
    sincosf(TWO_PI_OVER_N * (float)t, &s, &c);
    ct[t] = c; st[t] = s;
    if (t < NFREQ) {
#pragma unroll
        for (int o = 0; o < 8; ++o)
            sX[o * NFREQ + t] = Ch[((size_t)(ch * 8 + o) * NLAT + l) * NFREQ + t];
    }
    __syncthreads();
    float av[8];
#pragma unroll
    for (int o = 0; o < 8; ++o) av[o] = 0.f;
    for (int fq = 1; fq < 64; ++fq) {
        const int m = (fq * t) & 127;
        const float cr = ct[m], ci = st[m];
#pragma unroll
        for (int o = 0; o < 8; ++o) {
            const float2 v = sX[o * NFREQ + fq];
            av[o] = fmaf(v.x, cr, av[o]);
            av[o] = fmaf(-v.y, ci, av[o]);
        }
    }
    const float sg = (t & 1) ? -1.f : 1.f;
#pragma unroll
    for (int o = 0; o < 8; ++o) {
        const float res = (sX[o * NFREQ].x + sg * sX[o * NFREQ + 64].x + 2.f * av[o]) * (1.f / 128.f);
        dbuf[(((size_t)l * 64 + ch) * TOTAL_K + lvl * 8 + o) * NLON + t] = res;
    }
}

// K5: fused head-MLP + residual + FFN + residual. Block = (l, 8-lon tile).
__global__ __launch_bounds__(256, 1) void k5_head_ffn(
    const float* __restrict__ dbuf, const float* __restrict__ x,
    const float* __restrict__ hw1, const float* __restrict__ hb1,
    const float* __restrict__ hw2, const float* __restrict__ hb2,
    const float* __restrict__ fw0, const float* __restrict__ fb0,
    const float* __restrict__ fw1, const float* __restrict__ fb1,
    float* __restrict__ out) {
    const int l = blockIdx.x;
    const int pt = blockIdx.y;
    const int t = threadIdx.x;     // 256
    const int pos = t >> 5;        // 0..7
    const int lane = t & 31;
    const int p = pt * 8 + pos;

    __shared__ float sf[8][1537];          // feats per pos: [ch*24+K]
    __shared__ float sxl2[8][LEARN];
    __shared__ float sh[8][FFN_HID];

    for (int idx = t; idx < 1536 * 8; idx += 256) {
        const int row = idx >> 3;
        const int pp = idx & 7;
        sf[pp][row] = dbuf[((size_t)l * 1536 + row) * NLON + pt * 8 + pp];
    }
    __syncthreads();

#pragma unroll
    for (int s2 = 0; s2 < 2; ++s2) {
        const int ch = lane + 32 * s2;
        const int n = ch >> 4;
        float fr[TOTAL_K];
#pragma unroll
        for (int k = 0; k < TOTAL_K; ++k) fr[k] = sf[pos][ch * TOTAL_K + k];
        float ho = hb2[n];
        for (int m = 0; m < HEAD_HID; ++m) {
            float a = hb1[n * HEAD_HID + m];
#pragma unroll
            for (int k = 0; k < TOTAL_K; ++k)
                a = fmaf(fr[k], hw1[(n * TOTAL_K + k) * HEAD_HID + m], a);
            ho = fmaf(gelu_f(a), hw2[n * HEAD_HID + m], ho);
        }
        sxl2[pos][ch] = ho + x[(l * NLON + p) * MODEL_DIM + ch];
    }
    __syncthreads();

    const float sc0 = x[(l * NLON + p) * MODEL_DIM + 64];
    const float sc1 = x[(l * NLON + p) * MODEL_DIM + 65];

#pragma unroll
    for (int mm = 0; mm < 4; ++mm) {
        const int m = lane + 32 * mm;
        float a = fb0[m];
        for (int k = 0; k < LEARN; ++k)
            a = fmaf(sxl2[pos][k], fw0[k * FFN_HID + m], a);
        a = fmaf(sc0, fw0[64 * FFN_HID + m], a);
        a = fmaf(sc1, fw0[65 * FFN_HID + m], a);
        sh[pos][m] = gelu_f(a);
    }
    __syncthreads();

#pragma unroll
    for (int s2 = 0; s2 < 2; ++s2) {
        const int dch = lane + 32 * s2;
        float a = fb1[dch];
        for (int m = 0; m < FFN_HID; ++m)
            a = fmaf(sh[pos][m], fw1[m * LEARN + dch], a);
        out[(l * NLON + p) * MODEL_DIM + dch] = a + sxl2[pos][dch];
    }
    if (lane < 2) out[(l * NLON + p) * MODEL_DIM + 64 + lane] = lane ? sc1 : sc0;
}

extern "C" void kernel_launch(void* const* d_in, const int* in_sizes, int n_in,
                              void* d_out, int out_size, void* d_ws, size_t ws_size,
                              hipStream_t stream) {
    (void)in_sizes; (void)n_in; (void)out_size; (void)ws_size;
    const float* x = (const float*)d_in[0];
    const float* psi[3] = {(const float*)d_in[1], (const float*)d_in[2], (const float*)d_in[3]};
    const float* w[3] = {(const float*)d_in[4], (const float*)d_in[6], (const float*)d_in[8]};
    const float* b[3] = {(const float*)d_in[5], (const float*)d_in[7], (const float*)d_in[9]};
    const float* hw1 = (const float*)d_in[10];
    const float* hb1 = (const float*)d_in[11];
    const float* hw2 = (const float*)d_in[12];
    const float* hb2 = (const float*)d_in[13];
    const float* fw0 = (const float*)d_in[14];
    const float* fb0 = (const float*)d_in[15];
    const float* fw1 = (const float*)d_in[16];
    const float* fb1 = (const float*)d_in[17];
    float* out = (float*)d_out;

    // workspace carve-up, ~92 MB total
    float2* Xh = (float2*)d_ws;                 // 64*64*65            = 266240
    float2* Pp = Xh + 266240;                   // 64*20*8*65          = 665600
    float2* bufA = Pp + 665600;                 // 64*8*64*65          = 2129920
    float2* bufB = bufA + 2129920;              // 64*8*64*65
    float* dbuf = (float*)(bufB + 2129920);     // 64*64*24*128 floats
    u64* nzm = (u64*)(dbuf + (size_t)64 * 64 * 24 * 128);   // 448 masks

    k1_fft_x<<<dim3(64 * 64), dim3(128), 0, stream>>>(x, Xh);

    for (int lvl = 0; lvl < 3; ++lvl) {
        k0_mask<<<dim3(448), dim3(256), 0, stream>>>(psi[lvl], nzm);
        k2_dft<<<dim3(448), dim3(128), 0, stream>>>(psi[lvl], nzm, Pp);
        const float2* ob;
        if (lvl == 0) {
            k3_contract<1, 1><<<dim3(520), dim3(64, 8), 0, stream>>>(Pp, Xh, w[0], b[0], nzm, bufA);
            ob = bufA;
        } else if (lvl == 1) {
            k3_contract<8, 4><<<dim3(520), dim3(64, 8), 0, stream>>>(Pp, bufA, w[1], b[1], nzm, bufB);
            ob = bufB;
        } else {
            k3_contract<8, 4><<<dim3(520), dim3(64, 8), 0, stream>>>(Pp, bufB, w[2], b[2], nzm, bufA);
            ob = bufA;
        }
        k4_irfft<<<dim3(64 * 64), dim3(128), 0, stream>>>(ob, dbuf, lvl);
    }

    k5_head_ffn<<<dim3(64, 16), dim3(256), 0, stream>>>(
        dbuf, x, hw1, hb1, hw2, hb2, fw0, fb0, fw1, fb1, out);
}